// Round 7
// baseline (2154.886 us; speedup 1.0000x reference)
//
#include <hip/hip_runtime.h>

// 3-layer sparse conv, gather formulation, zero atomics.
// R7: conv1 redesigned as row-per-wave / channel-per-lane:
//  - output row is wave-uniform -> offset validity check is a SCALAR branch
//    (27 -> ~4.67 effective k iterations; invalid k costs ~4cyc, not 256 FMA)
//  - map transposed to t1[n1][28] -> s_load_dwordx4 row reads
//  - gathered x row (32B) wave-uniform -> s_load; FMA reads SGPR operand
//  - W1 column loads per-lane coalesced 256B, W1 (54KB) L1/L2-hot
//  - h1 store = one full 256B contiguous line per wave (kills write amp)
// conv2 (row-per-lane, W amortized across 64 rows) and conv3 (4-wave k-split,
// SGPR W) keep their structures: their valid densities (20%, 72%) make W
// amortization worth more than scalar skipping.

#define TPB 256

// m204 bijective XCD-chunk swizzle
__device__ __forceinline__ int xcd_chunk(int bid, int nwg) {
  int q = nwg >> 3, r = nwg & 7;
  int xcd = bid & 7, idx = bid >> 3;
  int base = (xcd < r) ? xcd * (q + 1) : r * (q + 1) + (xcd - r) * q;
  return base + idx;
}

// build for conv2/conv3: tbl[k][out] = in
__global__ void __launch_bounds__(TPB)
k_build(const int* __restrict__ mi, const int* __restrict__ mo,
        int* __restrict__ tbl, int L, int n_out) {
  int k = blockIdx.y;
  int p = blockIdx.x * TPB + threadIdx.x;
  if (p >= L) return;
  int out = mo[(size_t)k * L + p];
  bool valid = out < n_out;
  if (__ballot(valid) == 0ull) return;
  if (valid) tbl[(size_t)k * n_out + out] = mi[(size_t)k * L + p];
}

// build for conv1: transposed tbl[out][28], slot k
__global__ void __launch_bounds__(TPB)
k_build1(const int* __restrict__ mi, const int* __restrict__ mo,
         int* __restrict__ tbl, int L, int n1) {
  int k = blockIdx.y;
  int p = blockIdx.x * TPB + threadIdx.x;
  if (p >= L) return;
  int out = mo[(size_t)k * L + p];
  bool valid = out < n1;
  if (__ballot(valid) == 0ull) return;
  if (valid) tbl[(size_t)out * 28 + k] = mi[(size_t)k * L + p];
}

// conv1: 8 -> 64, 27 offsets. wave = output row (2 rows/wave), lane = channel.
__global__ void __launch_bounds__(TPB)
k_conv1(const float* __restrict__ x, const float* __restrict__ W1,
        const float* __restrict__ b1, const int* __restrict__ t1,
        float* __restrict__ h1, int n1) {
  int wgl = blockIdx.x * 4 + (threadIdx.x >> 6);   // global wave id
  int j = threadIdx.x & 63;
  float b1v = b1[j];
#pragma unroll 1
  for (int rr = 0; rr < 2; ++rr) {
    int r = __builtin_amdgcn_readfirstlane(wgl * 2 + rr);  // SGPR row id
    if (r >= n1) return;                                   // uniform exit
    const int4* trow = (const int4*)(t1 + (size_t)r * 28);
    int idxs[28];
#pragma unroll
    for (int q = 0; q < 7; ++q) *(int4*)&idxs[4 * q] = trow[q];  // s_load x7
    float acc = 0.f;
#pragma unroll
    for (int k = 0; k < 27; ++k) {
      int idx = idxs[k];                    // SGPR
      if (idx < 0) continue;                // scalar branch: ~free skip
      const float4* xs = (const float4*)(x + (size_t)idx * 8);  // uniform -> s_load
      float4 xa = xs[0], xb = xs[1];
      const float* __restrict__ Wc = W1 + k * 512 + j;  // per-lane coalesced cols
      acc = fmaf(xa.x, Wc[0 * 64], acc);
      acc = fmaf(xa.y, Wc[1 * 64], acc);
      acc = fmaf(xa.z, Wc[2 * 64], acc);
      acc = fmaf(xa.w, Wc[3 * 64], acc);
      acc = fmaf(xb.x, Wc[4 * 64], acc);
      acc = fmaf(xb.y, Wc[5 * 64], acc);
      acc = fmaf(xb.z, Wc[6 * 64], acc);
      acc = fmaf(xb.w, Wc[7 * 64], acc);
    }
    h1[(size_t)r * 64 + j] = fmaxf(acc + b1v, 0.f);   // full 256B line per wave
  }
}

// conv2: 64 -> 64, 8 offsets. row-per-lane, j-quarter per block (W2 amortized
// across the wave's 64 rows), XCD-chunk swizzled.
__global__ void __launch_bounds__(TPB)
k_conv2(const float* __restrict__ h1, const float* __restrict__ W2,
        const float* __restrict__ b2, const int* __restrict__ t2,
        float* __restrict__ h2, int n1, int n2, int nwg) {
  int b = xcd_chunk(blockIdx.x, nwg);
  int jq = b & 3, xb = b >> 2;
  int r = xb * TPB + threadIdx.x;
  if (r >= n2) return;
  int j0 = jq * 16;
  float acc[16];
#pragma unroll
  for (int j = 0; j < 16; ++j) acc[j] = 0.f;
#pragma unroll 1
  for (int k = 0; k < 8; ++k) {
    int idx = t2[(size_t)k * n2 + r];
    int row = idx >= 0 ? idx : n1;          // zero row
    const float4* xr = (const float4*)(h1 + (size_t)row * 64);
    const float* __restrict__ Wk = W2 + (size_t)k * 4096 + j0;
#pragma unroll 4
    for (int c = 0; c < 16; ++c) {
      float4 xv = xr[c];
#pragma unroll
      for (int j = 0; j < 16; ++j) {
        acc[j] = fmaf(xv.x, Wk[(4*c+0)*64 + j], acc[j]);
        acc[j] = fmaf(xv.y, Wk[(4*c+1)*64 + j], acc[j]);
        acc[j] = fmaf(xv.z, Wk[(4*c+2)*64 + j], acc[j]);
        acc[j] = fmaf(xv.w, Wk[(4*c+3)*64 + j], acc[j]);
      }
    }
  }
  float4* yr = (float4*)(h2 + (size_t)r * 64 + j0);
#pragma unroll
  for (int q = 0; q < 4; ++q) {
    float4 o;
    o.x = fmaxf(acc[4*q+0] + b2[j0+4*q+0], 0.f);
    o.y = fmaxf(acc[4*q+1] + b2[j0+4*q+1], 0.f);
    o.z = fmaxf(acc[4*q+2] + b2[j0+4*q+2], 0.f);
    o.w = fmaxf(acc[4*q+3] + b2[j0+4*q+3], 0.f);
    yr[q] = o;
  }
}

// conv3: 64 -> 8, 27 offsets. 64-row blocks, 4 waves k-split (k ≡ w mod 4),
// SGPR W3, padded-LDS reduce.
__global__ void __launch_bounds__(TPB)
k_conv3(const float* __restrict__ h2, const float* __restrict__ W3,
        const float* __restrict__ b3, const int* __restrict__ t3,
        float* __restrict__ out, int n2, int nwg) {
  __shared__ float red[4][64][9];
  int b = xcd_chunk(blockIdx.x, nwg);
  int w = __builtin_amdgcn_readfirstlane(threadIdx.x >> 6);
  int l = threadIdx.x & 63;
  int r = b * 64 + l;
  int rc = r < n2 ? r : n2 - 1;
  float acc[8];
#pragma unroll
  for (int j = 0; j < 8; ++j) acc[j] = 0.f;
  int nk = (w < 3) ? 7 : 6;
  int idx = t3[(size_t)w * n2 + rc];
#pragma unroll 1
  for (int i = 0; i < nk; ++i) {
    int k = w + 4 * i;
    int row = idx >= 0 ? idx : n2;
    if (i + 1 < nk) idx = t3[(size_t)(k + 4) * n2 + rc];
    const float4* xr = (const float4*)(h2 + (size_t)row * 64);
    const float* __restrict__ Wk = W3 + (size_t)k * 512;
#pragma unroll
    for (int c = 0; c < 16; ++c) {
      float4 xv = xr[c];
      float hv[4] = {xv.x, xv.y, xv.z, xv.w};
#pragma unroll
      for (int u = 0; u < 4; ++u)
#pragma unroll
        for (int j = 0; j < 8; ++j)
          acc[j] = fmaf(hv[u], Wk[(4*c+u)*8 + j], acc[j]);
    }
  }
#pragma unroll
  for (int j = 0; j < 8; ++j) red[w][l][j] = acc[j];
  __syncthreads();
#pragma unroll
  for (int t = threadIdx.x; t < 512; t += TPB) {
    int row = t >> 3, ch = t & 7;
    int g = b * 64 + row;
    if (g < n2) {
      float s = red[0][row][ch] + red[1][row][ch]
              + red[2][row][ch] + red[3][row][ch];
      out[(size_t)g * 8 + ch] = s + b3[ch];
    }
  }
}

extern "C" void kernel_launch(void* const* d_in, const int* in_sizes, int n_in,
                              void* d_out, int out_size, void* d_ws, size_t ws_size,
                              hipStream_t stream) {
  const float* feats = (const float*)d_in[0];
  const float* W1 = (const float*)d_in[1];
  const float* b1 = (const float*)d_in[2];
  const float* W2 = (const float*)d_in[3];
  const float* b2 = (const float*)d_in[4];
  const float* W3 = (const float*)d_in[5];
  const float* b3 = (const float*)d_in[6];
  const int* m1i = (const int*)d_in[7];
  const int* m1o = (const int*)d_in[8];
  const int* m2i = (const int*)d_in[9];
  const int* m2o = (const int*)d_in[10];
  const int* m3i = (const int*)d_in[11];
  const int* m3o = (const int*)d_in[12];

  int n1 = in_sizes[0] / 8;
  int L1 = in_sizes[7] / 27;
  int L2 = in_sizes[9] / 8;
  int L3 = in_sizes[11] / 27;
  int n2 = out_size / 8;

  // Workspace layout (t1 aliases the y2 region: t1 dead before conv2 writes y2)
  char* ws = (char*)d_ws;
  size_t y1_bytes = (size_t)(n1 + 1) * 64 * sizeof(float);
  size_t y2_bytes = (size_t)(n2 + 1) * 64 * sizeof(float);
  size_t t1_bytes = (size_t)n1 * 28 * sizeof(int);     // transposed [n1][28]
  size_t reg1_bytes = y2_bytes > t1_bytes ? y2_bytes : t1_bytes;
  float* y1 = (float*)ws;                              // h1: (n1+1) x 64
  float* y2 = (float*)(ws + y1_bytes);                 // h2: (n2+1) x 64
  int* t1 = (int*)(ws + y1_bytes);                     // alias (n1 x 28)
  int* t2 = (int*)(ws + y1_bytes + reg1_bytes);        // 8 x n2
  int* t3 = (int*)(ws + y1_bytes + reg1_bytes + (size_t)8 * n2 * sizeof(int));

  hipMemsetAsync(t1, 0xFF, t1_bytes, stream);
  hipMemsetAsync(t2, 0xFF, (size_t)8 * n2 * sizeof(int), stream);
  hipMemsetAsync(t3, 0xFF, (size_t)27 * n2 * sizeof(int), stream);

  k_build1<<<dim3((L1 + TPB - 1) / TPB, 27), TPB, 0, stream>>>(m1i, m1o, t1, L1, n1);
  k_build<<<dim3((L2 + TPB - 1) / TPB, 8), TPB, 0, stream>>>(m2i, m2o, t2, L2, n2);
  k_build<<<dim3((L3 + TPB - 1) / TPB, 27), TPB, 0, stream>>>(m3i, m3o, t3, L3, n2);

  // conv1: 2 rows per wave, 4 waves per block
  int nwaves1 = (n1 + 1) / 2;
  k_conv1<<<(nwaves1 + 3) / 4, TPB, 0, stream>>>(feats, W1, b1, t1, y1, n1);

  // zero rows for invalid gathers (y2's zero row lives inside the t1 alias
  // region, so write it only after conv1 has consumed t1)
  hipMemsetAsync(y1 + (size_t)n1 * 64, 0, 64 * sizeof(float), stream);
  hipMemsetAsync(y2 + (size_t)n2 * 64, 0, 64 * sizeof(float), stream);

  int nb2 = ((n2 + TPB - 1) / TPB) * 4;
  k_conv2<<<nb2, TPB, 0, stream>>>(y1, W2, b2, t2, y2, n1, n2, nb2);

  int nb3 = (n2 + 63) / 64;
  k_conv3<<<nb3, TPB, 0, stream>>>(y2, W3, b3, t3, (float*)d_out, n2, nb3);
}

// Round 8
// 568.851 us; speedup vs baseline: 3.7881x; 3.7881x over previous
//
#include <hip/hip_runtime.h>

// 3-layer sparse conv, gather formulation, zero atomics.
// R8: conv1 reverted to row-per-lane j-split x2 (R7's row-per-wave collapsed:
// VGPR 208, occ 9% — compiler won't scalar-allocate pointer-chased loads) and
// given a 1-deep rolling prefetch: k+1's idx + 32B x-row (8 VGPR buffer)
// issued before k's 512-cycle FMA block; masking applied at use. conv2 gets
// idx-only prefetch. conv3 keeps the R6 wave-k-split structure.

#define TPB 256

// m204 bijective XCD-chunk swizzle
__device__ __forceinline__ int xcd_chunk(int bid, int nwg) {
  int q = nwg >> 3, r = nwg & 7;
  int xcd = bid & 7, idx = bid >> 3;
  int base = (xcd < r) ? xcd * (q + 1) : r * (q + 1) + (xcd - r) * q;
  return base + idx;
}

__global__ void __launch_bounds__(TPB)
k_build(const int* __restrict__ mi, const int* __restrict__ mo,
        int* __restrict__ tbl, int L, int n_out) {
  int k = blockIdx.y;
  int p = blockIdx.x * TPB + threadIdx.x;
  if (p >= L) return;
  int out = mo[(size_t)k * L + p];
  bool valid = out < n_out;                 // pads point at dummy row n_out
  if (__ballot(valid) == 0ull) return;      // pads are a contiguous tail
  if (valid) tbl[(size_t)k * n_out + out] = mi[(size_t)k * L + p];
}

// conv1: 8 -> 64, 27 offsets. lane = output row, blockIdx.y = j-half (32 ch).
// Rolling 1-deep prefetch of next idx + next 32B x-row.
__global__ void __launch_bounds__(TPB)
k_conv1(const float* __restrict__ x, const float* __restrict__ W1,
        const float* __restrict__ b1, const int* __restrict__ t1,
        float* __restrict__ h1, int n1) {
  int r = blockIdx.x * TPB + threadIdx.x;
  if (r >= n1) return;
  int j0 = blockIdx.y * 32;
  float acc[32];
#pragma unroll
  for (int j = 0; j < 32; ++j) acc[j] = 0.f;

  int icur = t1[r];                                        // k=0 idx
  const float4* xp = (const float4*)(x + (size_t)(icur >= 0 ? icur : 0) * 8);
  float4 ca = xp[0], cb = xp[1];
  bool vcur = icur >= 0;
#pragma unroll 1
  for (int k = 0; k < 27; ++k) {
    // prefetch k+1 (unconditional loads; mask applied at use)
    int inext = (k < 26) ? t1[(size_t)(k + 1) * n1 + r] : -1;
    const float4* np = (const float4*)(x + (size_t)(inext >= 0 ? inext : 0) * 8);
    float4 na = np[0], nb = np[1];
    if (!vcur) { ca = make_float4(0.f,0.f,0.f,0.f); cb = make_float4(0.f,0.f,0.f,0.f); }
    if (__ballot(vcur) != 0ull) {
      float xv[8] = {ca.x, ca.y, ca.z, ca.w, cb.x, cb.y, cb.z, cb.w};
      const float* __restrict__ Wk = W1 + (size_t)k * 512 + j0;   // wave-uniform
#pragma unroll
      for (int i = 0; i < 8; ++i)
#pragma unroll
        for (int j = 0; j < 32; ++j)
          acc[j] = fmaf(xv[i], Wk[i * 64 + j], acc[j]);
    }
    ca = na; cb = nb; vcur = inext >= 0;
  }
  float4* yr = (float4*)(h1 + (size_t)r * 64 + j0);
#pragma unroll
  for (int q = 0; q < 8; ++q) {
    float4 o;
    o.x = fmaxf(acc[4*q+0] + b1[j0+4*q+0], 0.f);
    o.y = fmaxf(acc[4*q+1] + b1[j0+4*q+1], 0.f);
    o.z = fmaxf(acc[4*q+2] + b1[j0+4*q+2], 0.f);
    o.w = fmaxf(acc[4*q+3] + b1[j0+4*q+3], 0.f);
    yr[q] = o;
  }
}

// conv2: 64 -> 64, 8 offsets. row-per-lane, j-quarter per block, XCD-chunk
// swizzled; idx prefetched one k ahead to break the idx->row->load chain.
__global__ void __launch_bounds__(TPB)
k_conv2(const float* __restrict__ h1, const float* __restrict__ W2,
        const float* __restrict__ b2, const int* __restrict__ t2,
        float* __restrict__ h2, int n1, int n2, int nwg) {
  int b = xcd_chunk(blockIdx.x, nwg);
  int jq = b & 3, xb = b >> 2;
  int r = xb * TPB + threadIdx.x;
  if (r >= n2) return;
  int j0 = jq * 16;
  float acc[16];
#pragma unroll
  for (int j = 0; j < 16; ++j) acc[j] = 0.f;
  int idx = t2[r];                          // k=0
#pragma unroll 1
  for (int k = 0; k < 8; ++k) {
    int inext = (k < 7) ? t2[(size_t)(k + 1) * n2 + r] : 0;
    int row = idx >= 0 ? idx : n1;          // zero row
    const float4* xr = (const float4*)(h1 + (size_t)row * 64);
    const float* __restrict__ Wk = W2 + (size_t)k * 4096 + j0;
#pragma unroll 4
    for (int c = 0; c < 16; ++c) {
      float4 xv = xr[c];
#pragma unroll
      for (int j = 0; j < 16; ++j) {
        acc[j] = fmaf(xv.x, Wk[(4*c+0)*64 + j], acc[j]);
        acc[j] = fmaf(xv.y, Wk[(4*c+1)*64 + j], acc[j]);
        acc[j] = fmaf(xv.z, Wk[(4*c+2)*64 + j], acc[j]);
        acc[j] = fmaf(xv.w, Wk[(4*c+3)*64 + j], acc[j]);
      }
    }
    idx = inext;
  }
  float4* yr = (float4*)(h2 + (size_t)r * 64 + j0);
#pragma unroll
  for (int q = 0; q < 4; ++q) {
    float4 o;
    o.x = fmaxf(acc[4*q+0] + b2[j0+4*q+0], 0.f);
    o.y = fmaxf(acc[4*q+1] + b2[j0+4*q+1], 0.f);
    o.z = fmaxf(acc[4*q+2] + b2[j0+4*q+2], 0.f);
    o.w = fmaxf(acc[4*q+3] + b2[j0+4*q+3], 0.f);
    yr[q] = o;
  }
}

// conv3: 64 -> 8, 27 offsets. 64-row blocks, 4 waves k-split (k ≡ w mod 4),
// SGPR W3, padded-LDS reduce. (R6 structure, unchanged.)
__global__ void __launch_bounds__(TPB)
k_conv3(const float* __restrict__ h2, const float* __restrict__ W3,
        const float* __restrict__ b3, const int* __restrict__ t3,
        float* __restrict__ out, int n2, int nwg) {
  __shared__ float red[4][64][9];
  int b = xcd_chunk(blockIdx.x, nwg);
  int w = __builtin_amdgcn_readfirstlane(threadIdx.x >> 6);
  int l = threadIdx.x & 63;
  int r = b * 64 + l;
  int rc = r < n2 ? r : n2 - 1;
  float acc[8];
#pragma unroll
  for (int j = 0; j < 8; ++j) acc[j] = 0.f;
  int nk = (w < 3) ? 7 : 6;
  int idx = t3[(size_t)w * n2 + rc];
#pragma unroll 1
  for (int i = 0; i < nk; ++i) {
    int k = w + 4 * i;
    int row = idx >= 0 ? idx : n2;
    if (i + 1 < nk) idx = t3[(size_t)(k + 4) * n2 + rc];
    const float4* xr = (const float4*)(h2 + (size_t)row * 64);
    const float* __restrict__ Wk = W3 + (size_t)k * 512;
#pragma unroll
    for (int c = 0; c < 16; ++c) {
      float4 xv = xr[c];
      float hv[4] = {xv.x, xv.y, xv.z, xv.w};
#pragma unroll
      for (int u = 0; u < 4; ++u)
#pragma unroll
        for (int j = 0; j < 8; ++j)
          acc[j] = fmaf(hv[u], Wk[(4*c+u)*8 + j], acc[j]);
    }
  }
#pragma unroll
  for (int j = 0; j < 8; ++j) red[w][l][j] = acc[j];
  __syncthreads();
#pragma unroll
  for (int t = threadIdx.x; t < 512; t += TPB) {
    int row = t >> 3, ch = t & 7;
    int g = b * 64 + row;
    if (g < n2) {
      float s = red[0][row][ch] + red[1][row][ch]
              + red[2][row][ch] + red[3][row][ch];
      out[(size_t)g * 8 + ch] = s + b3[ch];
    }
  }
}

extern "C" void kernel_launch(void* const* d_in, const int* in_sizes, int n_in,
                              void* d_out, int out_size, void* d_ws, size_t ws_size,
                              hipStream_t stream) {
  const float* feats = (const float*)d_in[0];
  const float* W1 = (const float*)d_in[1];
  const float* b1 = (const float*)d_in[2];
  const float* W2 = (const float*)d_in[3];
  const float* b2 = (const float*)d_in[4];
  const float* W3 = (const float*)d_in[5];
  const float* b3 = (const float*)d_in[6];
  const int* m1i = (const int*)d_in[7];
  const int* m1o = (const int*)d_in[8];
  const int* m2i = (const int*)d_in[9];
  const int* m2o = (const int*)d_in[10];
  const int* m3i = (const int*)d_in[11];
  const int* m3o = (const int*)d_in[12];

  int n1 = in_sizes[0] / 8;
  int L1 = in_sizes[7] / 27;
  int L2 = in_sizes[9] / 8;
  int L3 = in_sizes[11] / 27;
  int n2 = out_size / 8;

  // Workspace layout (t1 aliases the y2 region: t1 dead before conv2 writes y2)
  char* ws = (char*)d_ws;
  size_t y1_bytes = (size_t)(n1 + 1) * 64 * sizeof(float);
  size_t y2_bytes = (size_t)(n2 + 1) * 64 * sizeof(float);
  size_t t1_bytes = (size_t)27 * n1 * sizeof(int);
  size_t reg1_bytes = y2_bytes > t1_bytes ? y2_bytes : t1_bytes;
  float* y1 = (float*)ws;                              // h1: (n1+1) x 64
  float* y2 = (float*)(ws + y1_bytes);                 // h2: (n2+1) x 64
  int* t1 = (int*)(ws + y1_bytes);                     // alias (27 x n1)
  int* t2 = (int*)(ws + y1_bytes + reg1_bytes);        // 8 x n2
  int* t3 = (int*)(ws + y1_bytes + reg1_bytes + (size_t)8 * n2 * sizeof(int));

  hipMemsetAsync(t1, 0xFF, t1_bytes, stream);
  hipMemsetAsync(t2, 0xFF, (size_t)8 * n2 * sizeof(int), stream);
  hipMemsetAsync(t3, 0xFF, (size_t)27 * n2 * sizeof(int), stream);

  k_build<<<dim3((L1 + TPB - 1) / TPB, 27), TPB, 0, stream>>>(m1i, m1o, t1, L1, n1);
  k_build<<<dim3((L2 + TPB - 1) / TPB, 8), TPB, 0, stream>>>(m2i, m2o, t2, L2, n2);
  k_build<<<dim3((L3 + TPB - 1) / TPB, 27), TPB, 0, stream>>>(m3i, m3o, t3, L3, n2);

  k_conv1<<<dim3((n1 + TPB - 1) / TPB, 2), TPB, 0, stream>>>(feats, W1, b1, t1, y1, n1);

  // zero rows for invalid gathers (y2's zero row lives inside the t1 alias
  // region, so write it only after conv1 has consumed t1)
  hipMemsetAsync(y1 + (size_t)n1 * 64, 0, 64 * sizeof(float), stream);
  hipMemsetAsync(y2 + (size_t)n2 * 64, 0, 64 * sizeof(float), stream);

  int nb2 = ((n2 + TPB - 1) / TPB) * 4;
  k_conv2<<<nb2, TPB, 0, stream>>>(y1, W2, b2, t2, y2, n1, n2, nb2);

  int nb3 = (n2 + 63) / 64;
  k_conv3<<<nb3, TPB, 0, stream>>>(y2, W3, b3, t3, (float*)d_out, n2, nb3);
}